// Round 2
// baseline (1897.243 us; speedup 1.0000x reference)
//
#include <hip/hip_runtime.h>
#include <hip/hip_bf16.h>

#define DEPTH   6
#define DIM     192
#define HEADS   12
#define DH      16
#define MLPD    768
#define SEQ     256
#define BATCH   32
#define ROWS    (BATCH*SEQ)   // 8192

typedef __attribute__((ext_vector_type(8))) short short8;
typedef __attribute__((ext_vector_type(4))) float f32x4;
typedef __hip_bfloat16 bf16_t;

__device__ __forceinline__ float b2f(bf16_t v){ return __bfloat162float(v); }
__device__ __forceinline__ bf16_t f2b(float v){ return __float2bfloat16(v); }
__device__ __forceinline__ ushort f2u(float v){
    union{ bf16_t b; ushort u; } w; w.b = __float2bfloat16(v); return w.u;
}
__device__ __forceinline__ float bfu2f(ushort u){
    union{ uint i; float f; } w; w.i = ((uint)u) << 16; return w.f;
}

// ---------------- residual init: copy x (fp32) into d_out (fp32 residual) ----
__global__ void copy_kernel(const float* __restrict__ x, float* __restrict__ xr, int n){
    int i = blockIdx.x*256 + threadIdx.x;
    if (i < n) xr[i] = x[i];
}

// ---------------- LayerNorm: 1 wave per row, 4 rows/block ----------------
__global__ __launch_bounds__(256) void ln_kernel(const float* __restrict__ xf,
        const float* __restrict__ g, const float* __restrict__ b,
        bf16_t* __restrict__ out){
    int lane = threadIdx.x & 63, wid = threadIdx.x >> 6;
    int row = blockIdx.x*4 + wid;
    const float* xr = xf + (size_t)row*DIM;
    float v0 = xr[lane], v1 = xr[lane+64], v2 = xr[lane+128];
    float s = v0+v1+v2;
    #pragma unroll
    for (int off=32; off; off>>=1) s += __shfl_xor(s, off, 64);
    float m = s*(1.0f/192.0f);
    float d0=v0-m, d1=v1-m, d2=v2-m;
    float q = d0*d0+d1*d1+d2*d2;
    #pragma unroll
    for (int off=32; off; off>>=1) q += __shfl_xor(q, off, 64);
    float inv = rsqrtf(q*(1.0f/192.0f) + 1e-5f);
    bf16_t* orow = out + (size_t)row*DIM;
    orow[lane]     = f2b(d0*inv*g[lane]     + b[lane]);
    orow[lane+64]  = f2b(d1*inv*g[lane+64]  + b[lane+64]);
    orow[lane+128] = f2b(d2*inv*g[lane+128] + b[lane+128]);
}

// ---------------- bf16 MFMA GEMM: C[M,Nc] = A[M,K](bf16) @ B[K,Nc](fp32 weights)
// EPI 0: store bf16. EPI 1: +bias, exact GELU, store bf16. EPI 2: xres += (acc+bias)*ls.
template<int EPI>
__global__ __launch_bounds__(256) void gemm_kernel(
        const bf16_t* __restrict__ A, const float* __restrict__ Bw,
        const float* __restrict__ bias, bf16_t* __restrict__ out,
        int K, int Nc, const float* __restrict__ ls, float* __restrict__ xres){
    __shared__ ushort As[64][40];   // [m][k], stride 40 -> 2-way bank alias only (free)
    __shared__ ushort Bs[64][40];   // [n][k] (transposed on store)
    int tid  = threadIdx.x;
    int lane = tid & 63, wid = tid >> 6;
    int wrow = wid >> 1, wcol = wid & 1;
    int bm = blockIdx.x*64, bn = blockIdx.y*64;
    int quad = lane >> 4, mr = lane & 15;
    int ar = tid >> 2, ac = (tid & 3)*8;   // A tile loader: 64x32 bf16
    int bk = tid >> 3, bn8 = (tid & 7)*8;  // B tile loader: 32x64 fp32 -> bf16
    f32x4 acc[2][2] = {};
    for (int k0 = 0; k0 < K; k0 += 32){
        uint4 av = *(const uint4*)(A + (size_t)(bm+ar)*K + k0 + ac);
        const float* brow = Bw + (size_t)(k0+bk)*Nc + bn + bn8;
        float4 f0 = *(const float4*)(brow);
        float4 f1 = *(const float4*)(brow + 4);
        *(uint4*)&As[ar][ac] = av;
        Bs[bn8+0][bk] = f2u(f0.x); Bs[bn8+1][bk] = f2u(f0.y);
        Bs[bn8+2][bk] = f2u(f0.z); Bs[bn8+3][bk] = f2u(f0.w);
        Bs[bn8+4][bk] = f2u(f1.x); Bs[bn8+5][bk] = f2u(f1.y);
        Bs[bn8+6][bk] = f2u(f1.z); Bs[bn8+7][bk] = f2u(f1.w);
        __syncthreads();
        // A frag: lane holds A[m=mr][k=quad*8+j]; B frag: B[k=quad*8+j][n=mr]
        short8 a0 = *(const short8*)&As[wrow*32 +      mr][quad*8];
        short8 a1 = *(const short8*)&As[wrow*32 + 16 + mr][quad*8];
        short8 b0 = *(const short8*)&Bs[wcol*32 +      mr][quad*8];
        short8 b1 = *(const short8*)&Bs[wcol*32 + 16 + mr][quad*8];
        acc[0][0] = __builtin_amdgcn_mfma_f32_16x16x32_bf16(a0, b0, acc[0][0], 0,0,0);
        acc[0][1] = __builtin_amdgcn_mfma_f32_16x16x32_bf16(a0, b1, acc[0][1], 0,0,0);
        acc[1][0] = __builtin_amdgcn_mfma_f32_16x16x32_bf16(a1, b0, acc[1][0], 0,0,0);
        acc[1][1] = __builtin_amdgcn_mfma_f32_16x16x32_bf16(a1, b1, acc[1][1], 0,0,0);
        __syncthreads();
    }
    // C/D layout: col = lane&15, row = quad*4 + t   [measured m89/m91]
    #pragma unroll
    for (int r=0; r<2; r++){
        #pragma unroll
        for (int c=0; c<2; c++){
            int col = bn + wcol*32 + c*16 + mr;
            float bv = (EPI >= 1) ? bias[col] : 0.f;
            float lv = (EPI == 2) ? ls[col]   : 0.f;
            #pragma unroll
            for (int t=0; t<4; t++){
                int row = bm + wrow*32 + r*16 + quad*4 + t;
                float v = acc[r][c][t];
                if (EPI == 0){
                    out[(size_t)row*Nc + col] = f2b(v);
                } else if (EPI == 1){
                    float z = v + bv;
                    out[(size_t)row*Nc + col] = f2b(0.5f*z*(1.0f + erff(z*0.70710678118654752f)));
                } else {
                    float z = v + bv;
                    xres[(size_t)row*DIM + col] += z*lv;
                }
            }
        }
    }
}

// ---------------- fused talking-heads LSA attention ----------------
// one block per (batch b, 4-row i-tile). scores s[h][i][j] fp32 in LDS.
__global__ __launch_bounds__(256) void attn_kernel(
        const bf16_t* __restrict__ qb, const bf16_t* __restrict__ kvb,
        const float* __restrict__ lsa, const float* __restrict__ pre,
        const float* __restrict__ post, bf16_t* __restrict__ ob){
    __shared__ float s[HEADS][4][SEQ+1];   // +1 pad: spreads the 256-stride across banks
    __shared__ float qs[4][DIM];
    __shared__ float pre_s[HEADS*HEADS];
    __shared__ float post_s[HEADS*HEADS];
    int tid = threadIdx.x;
    int b  = blockIdx.x >> 6;          // SEQ/4 = 64 tiles per batch
    int i0 = (blockIdx.x & 63)*4;
    if (tid < HEADS*HEADS){ pre_s[tid] = pre[tid]; post_s[tid] = post[tid]; }
    // load Q rows, fold per-head lsa scale
    for (int e = tid; e < 4*DIM; e += 256){
        int i = e/DIM, c = e - i*DIM, h = c >> 4;
        qs[i][c] = b2f(qb[(size_t)(b*SEQ + i0 + i)*DIM + c]) * lsa[h];
    }
    __syncthreads();
    // ---- dots[h][i][j] = scaled q.k, diag -> -1e-9 ----
    {
        int j = tid;   // 256 threads = 256 j's
        const bf16_t* krow = kvb + (size_t)(b*SEQ + j)*(2*DIM);
        #pragma unroll
        for (int h=0; h<HEADS; h++){
            float kr[DH];
            union { uint4 v; ushort u[8]; } w0, w1;
            w0.v = *(const uint4*)(krow + h*DH);
            w1.v = *(const uint4*)(krow + h*DH + 8);
            #pragma unroll
            for (int d=0; d<8; d++){ kr[d] = bfu2f(w0.u[d]); kr[d+8] = bfu2f(w1.u[d]); }
            #pragma unroll
            for (int i=0; i<4; i++){
                float a = 0.f;
                #pragma unroll
                for (int d=0; d<DH; d++) a += qs[i][h*DH + d]*kr[d];
                s[h][i][j] = (j == i0 + i) ? -1e-9f : a;
            }
        }
    }
    __syncthreads();
    // ---- mix_pre: s[g] = sum_h s[h]*pre[h][g], per (i,j) owned by one thread ----
    #pragma unroll
    for (int p=0; p<4; p++){
        int i = p, j = tid;
        float t[HEADS];
        #pragma unroll
        for (int h=0; h<HEADS; h++) t[h] = s[h][i][j];
        #pragma unroll
        for (int g=0; g<HEADS; g++){
            float a = 0.f;
            #pragma unroll
            for (int h=0; h<HEADS; h++) a += t[h]*pre_s[h*HEADS + g];
            s[g][i][j] = a;
        }
    }
    __syncthreads();
    // ---- softmax over j, one wave per (g,i) row ----
    {
        int lane = tid & 63, wid = tid >> 6;
        for (int row = wid; row < HEADS*4; row += 4){
            float* sp = &s[row>>2][row&3][0];
            float v0=sp[lane], v1=sp[lane+64], v2=sp[lane+128], v3=sp[lane+192];
            float m = fmaxf(fmaxf(v0,v1), fmaxf(v2,v3));
            #pragma unroll
            for (int off=32; off; off>>=1) m = fmaxf(m, __shfl_xor(m, off, 64));
            v0=__expf(v0-m); v1=__expf(v1-m); v2=__expf(v2-m); v3=__expf(v3-m);
            float su = v0+v1+v2+v3;
            #pragma unroll
            for (int off=32; off; off>>=1) su += __shfl_xor(su, off, 64);
            float r = 1.0f/su;
            sp[lane]=v0*r; sp[lane+64]=v1*r; sp[lane+128]=v2*r; sp[lane+192]=v3*r;
        }
    }
    __syncthreads();
    // ---- mix_post ----
    #pragma unroll
    for (int p=0; p<4; p++){
        int i = p, j = tid;
        float t[HEADS];
        #pragma unroll
        for (int h=0; h<HEADS; h++) t[h] = s[h][i][j];
        #pragma unroll
        for (int g=0; g<HEADS; g++){
            float a = 0.f;
            #pragma unroll
            for (int h=0; h<HEADS; h++) a += t[h]*post_s[h*HEADS + g];
            s[g][i][j] = a;
        }
    }
    __syncthreads();
    // ---- o[i][c] = sum_j a2[h][i][j] * v[j][c],  c = h*16+d ----
    {
        const ushort* vbase = (const ushort*)(kvb + (size_t)(b*SEQ)*(2*DIM) + DIM);
        for (int e = tid; e < 4*DIM; e += 256){
            int i = e/DIM, c = e - i*DIM, h = c >> 4;
            float a = 0.f;
            const float* sp = &s[h][i][0];
            #pragma unroll 4
            for (int j=0; j<SEQ; j++) a += sp[j]*bfu2f(vbase[(size_t)j*(2*DIM) + c]);
            ob[(size_t)(b*SEQ + i0 + i)*DIM + c] = f2b(a);
        }
    }
}

extern "C" void kernel_launch(void* const* d_in, const int* in_sizes, int n_in,
                              void* d_out, int out_size, void* d_ws, size_t ws_size,
                              hipStream_t stream){
    const float* x    = (const float*)d_in[0];
    const float* ln1g = (const float*)d_in[1];
    const float* ln1b = (const float*)d_in[2];
    const float* Wq   = (const float*)d_in[3];
    const float* Wkv  = (const float*)d_in[4];
    const float* lsa  = (const float*)d_in[5];
    const float* pre  = (const float*)d_in[6];
    const float* post = (const float*)d_in[7];
    const float* Wo   = (const float*)d_in[8];
    const float* bo   = (const float*)d_in[9];
    const float* ls1  = (const float*)d_in[10];
    const float* ln2g = (const float*)d_in[11];
    const float* ln2b = (const float*)d_in[12];
    const float* W1   = (const float*)d_in[13];
    const float* b1   = (const float*)d_in[14];
    const float* W2   = (const float*)d_in[15];
    const float* b2   = (const float*)d_in[16];
    const float* ls2  = (const float*)d_in[17];
    float* xres = (float*)d_out;                  // fp32 residual lives in d_out

    char* ws = (char*)d_ws;
    bf16_t* h   = (bf16_t*)ws; ws += (size_t)ROWS*DIM*2;      // LN output
    bf16_t* qb  = (bf16_t*)ws; ws += (size_t)ROWS*DIM*2;      // Q
    bf16_t* kvb = (bf16_t*)ws; ws += (size_t)ROWS*2*DIM*2;    // K|V
    bf16_t* ob  = (bf16_t*)ws; ws += (size_t)ROWS*DIM*2;      // attn out
    bf16_t* fb  = (bf16_t*)ws; ws += (size_t)ROWS*MLPD*2;     // MLP hidden

    int ntot = ROWS*DIM;
    copy_kernel<<<(ntot+255)/256, 256, 0, stream>>>(x, xres, ntot);
    for (int l = 0; l < DEPTH; l++){
        ln_kernel<<<ROWS/4, 256, 0, stream>>>(xres, ln1g + l*DIM, ln1b + l*DIM, h);
        gemm_kernel<0><<<dim3(ROWS/64, DIM/64),  256, 0, stream>>>(h, Wq  + (size_t)l*DIM*DIM,   nullptr, qb,  DIM,  DIM,  nullptr, nullptr);
        gemm_kernel<0><<<dim3(ROWS/64, 384/64),  256, 0, stream>>>(h, Wkv + (size_t)l*DIM*2*DIM, nullptr, kvb, DIM,  2*DIM, nullptr, nullptr);
        attn_kernel<<<BATCH*(SEQ/4), 256, 0, stream>>>(qb, kvb, lsa + l*HEADS,
                pre + l*HEADS*HEADS, post + l*HEADS*HEADS, ob);
        gemm_kernel<2><<<dim3(ROWS/64, DIM/64),  256, 0, stream>>>(ob, Wo + (size_t)l*DIM*DIM, bo + l*DIM, nullptr, DIM, DIM, ls1 + l*DIM, xres);
        ln_kernel<<<ROWS/4, 256, 0, stream>>>(xres, ln2g + l*DIM, ln2b + l*DIM, h);
        gemm_kernel<1><<<dim3(ROWS/64, MLPD/64), 256, 0, stream>>>(h,  W1 + (size_t)l*DIM*MLPD, b1 + l*MLPD, fb, DIM, MLPD, nullptr, nullptr);
        gemm_kernel<2><<<dim3(ROWS/64, DIM/64),  256, 0, stream>>>(fb, W2 + (size_t)l*MLPD*DIM, b2 + l*DIM, nullptr, MLPD, DIM, ls2 + l*DIM, xres);
    }
}

// Round 3
// 843.697 us; speedup vs baseline: 2.2487x; 2.2487x over previous
//
#include <hip/hip_runtime.h>
#include <hip/hip_bf16.h>

#define DEPTH   6
#define DIM     192
#define HEADS   12
#define DH      16
#define MLPD    768
#define SEQ     256
#define BATCH   32
#define ROWS    (BATCH*SEQ)   // 8192

typedef __attribute__((ext_vector_type(8))) short short8;
typedef __attribute__((ext_vector_type(4))) float f32x4;
typedef __attribute__((ext_vector_type(4))) _Float16 half4;
typedef __hip_bfloat16 bf16_t;
typedef _Float16 f16_t;

__device__ __forceinline__ float b2f(bf16_t v){ return __bfloat162float(v); }
__device__ __forceinline__ bf16_t f2b(float v){ return __float2bfloat16(v); }
__device__ __forceinline__ ushort f2u(float v){
    union{ bf16_t b; ushort u; } w; w.b = __float2bfloat16(v); return w.u;
}
__device__ __forceinline__ f16_t u2h(ushort u){ union{ ushort u; f16_t h; } w; w.u = u; return w.h; }
__device__ __forceinline__ ushort h2u(f16_t h){ union{ ushort u; f16_t h; } w; w.h = h; return w.u; }

// ---------------- residual init: copy x (fp32) into d_out (fp32 residual) ----
__global__ void copy_kernel(const float* __restrict__ x, float* __restrict__ xr, int n){
    int i = blockIdx.x*256 + threadIdx.x;
    if (i < n) xr[i] = x[i];
}

// ---------------- LayerNorm: 1 wave per row, 4 rows/block ----------------
__global__ __launch_bounds__(256) void ln_kernel(const float* __restrict__ xf,
        const float* __restrict__ g, const float* __restrict__ b,
        bf16_t* __restrict__ out){
    int lane = threadIdx.x & 63, wid = threadIdx.x >> 6;
    int row = blockIdx.x*4 + wid;
    const float* xr = xf + (size_t)row*DIM;
    float v0 = xr[lane], v1 = xr[lane+64], v2 = xr[lane+128];
    float s = v0+v1+v2;
    #pragma unroll
    for (int off=32; off; off>>=1) s += __shfl_xor(s, off, 64);
    float m = s*(1.0f/192.0f);
    float d0=v0-m, d1=v1-m, d2=v2-m;
    float q = d0*d0+d1*d1+d2*d2;
    #pragma unroll
    for (int off=32; off; off>>=1) q += __shfl_xor(q, off, 64);
    float inv = rsqrtf(q*(1.0f/192.0f) + 1e-5f);
    bf16_t* orow = out + (size_t)row*DIM;
    orow[lane]     = f2b(d0*inv*g[lane]     + b[lane]);
    orow[lane+64]  = f2b(d1*inv*g[lane+64]  + b[lane+64]);
    orow[lane+128] = f2b(d2*inv*g[lane+128] + b[lane+128]);
}

// ---------------- bf16 MFMA GEMM: C[M,Nc] = A[M,K](bf16) @ B[K,Nc](fp32 weights)
// EPI 0: store bf16. EPI 1: +bias, GELU, store bf16. EPI 2: xres += (acc+bias)*ls. EPI 3: store fp16.
template<int EPI>
__global__ __launch_bounds__(256) void gemm_kernel(
        const bf16_t* __restrict__ A, const float* __restrict__ Bw,
        const float* __restrict__ bias, bf16_t* __restrict__ out,
        int K, int Nc, const float* __restrict__ ls, float* __restrict__ xres){
    __shared__ ushort As[64][40];   // [m][k], stride 40 -> 2-way bank alias only (free)
    __shared__ ushort Bs[64][40];   // [n][k] (transposed on store)
    int tid  = threadIdx.x;
    int lane = tid & 63, wid = tid >> 6;
    int wrow = wid >> 1, wcol = wid & 1;
    int bm = blockIdx.x*64, bn = blockIdx.y*64;
    int quad = lane >> 4, mr = lane & 15;
    int ar = tid >> 2, ac = (tid & 3)*8;   // A tile loader: 64x32 bf16
    int bk = tid >> 3, bn8 = (tid & 7)*8;  // B tile loader: 32x64 fp32 -> bf16
    f32x4 acc[2][2] = {};
    for (int k0 = 0; k0 < K; k0 += 32){
        uint4 av = *(const uint4*)(A + (size_t)(bm+ar)*K + k0 + ac);
        const float* brow = Bw + (size_t)(k0+bk)*Nc + bn + bn8;
        float4 f0 = *(const float4*)(brow);
        float4 f1 = *(const float4*)(brow + 4);
        *(uint4*)&As[ar][ac] = av;
        Bs[bn8+0][bk] = f2u(f0.x); Bs[bn8+1][bk] = f2u(f0.y);
        Bs[bn8+2][bk] = f2u(f0.z); Bs[bn8+3][bk] = f2u(f0.w);
        Bs[bn8+4][bk] = f2u(f1.x); Bs[bn8+5][bk] = f2u(f1.y);
        Bs[bn8+6][bk] = f2u(f1.z); Bs[bn8+7][bk] = f2u(f1.w);
        __syncthreads();
        short8 a0 = *(const short8*)&As[wrow*32 +      mr][quad*8];
        short8 a1 = *(const short8*)&As[wrow*32 + 16 + mr][quad*8];
        short8 b0 = *(const short8*)&Bs[wcol*32 +      mr][quad*8];
        short8 b1 = *(const short8*)&Bs[wcol*32 + 16 + mr][quad*8];
        acc[0][0] = __builtin_amdgcn_mfma_f32_16x16x32_bf16(a0, b0, acc[0][0], 0,0,0);
        acc[0][1] = __builtin_amdgcn_mfma_f32_16x16x32_bf16(a0, b1, acc[0][1], 0,0,0);
        acc[1][0] = __builtin_amdgcn_mfma_f32_16x16x32_bf16(a1, b0, acc[1][0], 0,0,0);
        acc[1][1] = __builtin_amdgcn_mfma_f32_16x16x32_bf16(a1, b1, acc[1][1], 0,0,0);
        __syncthreads();
    }
    #pragma unroll
    for (int r=0; r<2; r++){
        #pragma unroll
        for (int c=0; c<2; c++){
            int col = bn + wcol*32 + c*16 + mr;
            float bv = (EPI == 1 || EPI == 2) ? bias[col] : 0.f;
            float lv = (EPI == 2) ? ls[col]   : 0.f;
            #pragma unroll
            for (int t=0; t<4; t++){
                int row = bm + wrow*32 + r*16 + quad*4 + t;
                float v = acc[r][c][t];
                if (EPI == 0){
                    out[(size_t)row*Nc + col] = f2b(v);
                } else if (EPI == 3){
                    ((f16_t*)out)[(size_t)row*Nc + col] = (f16_t)v;
                } else if (EPI == 1){
                    float z = v + bv;
                    out[(size_t)row*Nc + col] = f2b(0.5f*z*(1.0f + erff(z*0.70710678118654752f)));
                } else {
                    float z = v + bv;
                    xres[(size_t)row*DIM + col] += z*lv;
                }
            }
        }
    }
}

// ---------------- fully-MFMA fused talking-heads LSA attention ----------------
// block = (batch, 16-row i-tile), 512 threads / 8 waves.
// LDS layout (ushort elems): S[h][i][j] = h*SLAB + i*IST + j  (h<12, i<16, j<256)
//   strides padded so quad-strided frag reads land <=2-way on banks.
// mix MFMAs read h=0..15 (k-dim 16): rows 12..15 land in the staged/zeroed region
// past S (finite f16) and are multiplied by the zero-padded preT/postT rows.
#define SLAB    4488
#define IST     280
#define KV_OFF  53856
#define ROWP    200
#define Q_OFF   66656      // KV_OFF + 64*200
#define PRE_OFF 69856      // Q_OFF + 16*200
#define POST_OFF 70112
#define LTOT    71776      // covers max mix OOB read (71775)

__global__ __launch_bounds__(512, 1) void attn_kernel(
        const f16_t* __restrict__ qb, const f16_t* __restrict__ kvb,
        const float* __restrict__ lsa, const float* __restrict__ pre,
        const float* __restrict__ post, bf16_t* __restrict__ ob){
    __shared__ ushort L[LTOT];
    int tid  = threadIdx.x;
    int lane = tid & 63, w = tid >> 6;
    int quad = lane >> 4, nr = lane & 15;
    int b  = blockIdx.x >> 4;
    int i0 = (blockIdx.x & 15) << 4;

    // zero everything past S (row pads + tail are read by mix OOB / B-frags)
    {
        uint* Z = (uint*)&L[KV_OFF];
        for (int k = tid; k < (LTOT - KV_OFF)/2; k += 512) Z[k] = 0;
    }
    __syncthreads();

    // stage Q (lsa folded) with tid<384; preT/postT (transposed, zero-padded) with tid>=384
    if (tid < 384){
        int e = tid*8, i = e/DIM, d = e%DIM, hh = d >> 4;
        float sc = lsa[hh];
        union { uint4 v; f16_t h[8]; } iv, ov;
        iv.v = *(const uint4*)(qb + (size_t)(b*SEQ + i0 + i)*DIM + d);
        #pragma unroll
        for (int u=0; u<8; u++) ov.h[u] = (f16_t)((float)iv.h[u]*sc);
        *(uint4*)&L[Q_OFF + i*ROWP + d] = ov.v;
    } else {
        for (int k = tid-384; k < 512; k += 128){
            int gg = (k & 255) >> 4, hh = k & 15;
            float v = 0.f;
            if (gg < 12 && hh < 12) v = (k < 256) ? pre[hh*12+gg] : post[hh*12+gg];
            L[(k < 256 ? PRE_OFF : (POST_OFF-256)) + k] = h2u((f16_t)v);
        }
    }
    // stage K chunk 0 (all threads; disjoint region from Q/pp)
    auto stage_kv = [&](int c, int coloff){
        #pragma unroll
        for (int s = 0; s < 3; s++){
            int e = (tid + s*512)*8;
            int j = e/DIM, d = e%DIM;
            uint4 v = *(const uint4*)(kvb + (size_t)(b*SEQ + c*64 + j)*(2*DIM) + coloff + d);
            *(uint4*)&L[KV_OFF + j*ROWP + d] = v;
        }
    };
    stage_kv(0, 0);
    __syncthreads();

    // persistent frags
    int hbase = (w >> 2)*6;
    half4 qf[6];
    #pragma unroll
    for (int hh=0; hh<6; hh++)
        qf[hh] = *(const half4*)&L[Q_OFF + nr*ROWP + (hbase+hh)*16 + quad*4];
    half4 preTf  = *(const half4*)&L[PRE_OFF  + nr*16 + quad*4];
    half4 postTf = *(const half4*)&L[POST_OFF + nr*16 + quad*4];

    // ---- P1: QK^T per head, diag fix, logits -> S (f16) ----
    int jsl = w & 3;
    for (int c = 0; c < 4; c++){
        int j0g = c*64 + jsl*16;
        #pragma unroll
        for (int hh=0; hh<6; hh++){
            int h = hbase + hh;
            half4 bv = *(const half4*)&L[KV_OFF + (jsl*16 + nr)*ROWP + h*16 + quad*4];
            f32x4 a = __builtin_amdgcn_mfma_f32_16x16x16f16(qf[hh], bv, (f32x4){0,0,0,0}, 0,0,0);
            int jg = j0g + nr;
            #pragma unroll
            for (int t=0; t<4; t++){
                float v = a[t];
                if (i0 + quad*4 + t == jg) v = -1e-9f;
                L[h*SLAB + (quad*4+t)*IST + jg] = h2u((f16_t)v);
            }
        }
        __syncthreads();
        if (c < 3){ stage_kv(c+1, 0); __syncthreads(); }
    }

    // ---- P2: mix_pre via MFMA, in-place per 16-cell block ----
    for (int s = 0; s < 32; s++){
        int cb = s*8 + w;                 // unique cell-block per (s,w)
        int i = cb >> 4, jb = cb & 15;
        int colbase = i*IST + jb*16 + nr;
        half4 bv;
        #pragma unroll
        for (int t=0; t<4; t++) bv[t] = u2h(L[(quad*4+t)*SLAB + colbase]);
        f32x4 cc = __builtin_amdgcn_mfma_f32_16x16x16f16(preTf, bv, (f32x4){0,0,0,0}, 0,0,0);
        if (quad < 3){
            #pragma unroll
            for (int t=0; t<4; t++) L[(quad*4+t)*SLAB + colbase] = h2u((f16_t)cc[t]);
        }
    }
    __syncthreads();

    // ---- softmax over j (no max-sub: mixed logits are O(1)) ----
    for (int r = w; r < 192; r += 8){
        int g = r >> 4, i = r & 15;
        ushort* sp = &L[g*SLAB + i*IST];
        ushort4 uv = *(ushort4*)&sp[lane*4];
        float e0 = __expf((float)u2h(uv.x));
        float e1 = __expf((float)u2h(uv.y));
        float e2 = __expf((float)u2h(uv.z));
        float e3 = __expf((float)u2h(uv.w));
        float ssum = e0+e1+e2+e3;
        #pragma unroll
        for (int off=32; off; off>>=1) ssum += __shfl_xor(ssum, off, 64);
        float rin = 1.0f/ssum;
        uv.x = h2u((f16_t)(e0*rin)); uv.y = h2u((f16_t)(e1*rin));
        uv.z = h2u((f16_t)(e2*rin)); uv.w = h2u((f16_t)(e3*rin));
        *(ushort4*)&sp[lane*4] = uv;
    }
    __syncthreads();

    // ---- P3: mix_post via MFMA, in-place ----
    for (int s = 0; s < 32; s++){
        int cb = s*8 + w;
        int i = cb >> 4, jb = cb & 15;
        int colbase = i*IST + jb*16 + nr;
        half4 bv;
        #pragma unroll
        for (int t=0; t<4; t++) bv[t] = u2h(L[(quad*4+t)*SLAB + colbase]);
        f32x4 cc = __builtin_amdgcn_mfma_f32_16x16x16f16(postTf, bv, (f32x4){0,0,0,0}, 0,0,0);
        if (quad < 3){
            #pragma unroll
            for (int t=0; t<4; t++) L[(quad*4+t)*SLAB + colbase] = h2u((f16_t)cc[t]);
        }
    }
    __syncthreads();

    // ---- P4: O = P @ V via MFMA chains over j ----
    f32x4 oacc[2] = {{0,0,0,0},{0,0,0,0}};
    int g0 = w, g1 = (w < 4) ? 8 + w : -1;
    for (int c = 0; c < 4; c++){
        stage_kv(c, DIM);     // V columns
        __syncthreads();
        #pragma unroll
        for (int sl = 0; sl < 2; sl++){
            int g = sl ? g1 : g0;
            if (g < 0) continue;
            #pragma unroll
            for (int ks = 0; ks < 4; ks++){
                int jl = ks*16 + quad*4;
                half4 av = *(const half4*)&L[g*SLAB + nr*IST + c*64 + jl];
                half4 bv;
                #pragma unroll
                for (int t=0; t<4; t++) bv[t] = u2h(L[KV_OFF + (jl+t)*ROWP + g*16 + nr]);
                oacc[sl] = __builtin_amdgcn_mfma_f32_16x16x16f16(av, bv, oacc[sl], 0,0,0);
            }
        }
        __syncthreads();
    }
    #pragma unroll
    for (int sl = 0; sl < 2; sl++){
        int g = sl ? g1 : g0;
        if (g < 0) continue;
        #pragma unroll
        for (int t=0; t<4; t++){
            int i = quad*4 + t;
            ob[(size_t)(b*SEQ + i0 + i)*DIM + g*16 + nr] = f2b(oacc[sl][t]);
        }
    }
}

extern "C" void kernel_launch(void* const* d_in, const int* in_sizes, int n_in,
                              void* d_out, int out_size, void* d_ws, size_t ws_size,
                              hipStream_t stream){
    const float* x    = (const float*)d_in[0];
    const float* ln1g = (const float*)d_in[1];
    const float* ln1b = (const float*)d_in[2];
    const float* Wq   = (const float*)d_in[3];
    const float* Wkv  = (const float*)d_in[4];
    const float* lsa  = (const float*)d_in[5];
    const float* pre  = (const float*)d_in[6];
    const float* post = (const float*)d_in[7];
    const float* Wo   = (const float*)d_in[8];
    const float* bo   = (const float*)d_in[9];
    const float* ls1  = (const float*)d_in[10];
    const float* ln2g = (const float*)d_in[11];
    const float* ln2b = (const float*)d_in[12];
    const float* W1   = (const float*)d_in[13];
    const float* b1   = (const float*)d_in[14];
    const float* W2   = (const float*)d_in[15];
    const float* b2   = (const float*)d_in[16];
    const float* ls2  = (const float*)d_in[17];
    float* xres = (float*)d_out;                  // fp32 residual lives in d_out

    char* ws = (char*)d_ws;
    bf16_t* h   = (bf16_t*)ws; ws += (size_t)ROWS*DIM*2;      // LN output (bf16)
    f16_t*  qb  = (f16_t*)ws;  ws += (size_t)ROWS*DIM*2;      // Q (fp16)
    f16_t*  kvb = (f16_t*)ws;  ws += (size_t)ROWS*2*DIM*2;    // K|V (fp16)
    bf16_t* ob  = (bf16_t*)ws; ws += (size_t)ROWS*DIM*2;      // attn out (bf16)
    bf16_t* fb  = (bf16_t*)ws; ws += (size_t)ROWS*MLPD*2;     // MLP hidden (bf16)

    int ntot = ROWS*DIM;
    copy_kernel<<<(ntot+255)/256, 256, 0, stream>>>(x, xres, ntot);
    for (int l = 0; l < DEPTH; l++){
        ln_kernel<<<ROWS/4, 256, 0, stream>>>(xres, ln1g + l*DIM, ln1b + l*DIM, h);
        gemm_kernel<3><<<dim3(ROWS/64, DIM/64),  256, 0, stream>>>(h, Wq  + (size_t)l*DIM*DIM,   nullptr, (bf16_t*)qb,  DIM, DIM,   nullptr, nullptr);
        gemm_kernel<3><<<dim3(ROWS/64, 384/64),  256, 0, stream>>>(h, Wkv + (size_t)l*DIM*2*DIM, nullptr, (bf16_t*)kvb, DIM, 2*DIM, nullptr, nullptr);
        attn_kernel<<<BATCH*(SEQ/16), 512, 0, stream>>>(qb, kvb, lsa + l*HEADS,
                pre + l*HEADS*HEADS, post + l*HEADS*HEADS, ob);
        gemm_kernel<2><<<dim3(ROWS/64, DIM/64),  256, 0, stream>>>(ob, Wo + (size_t)l*DIM*DIM, bo + l*DIM, nullptr, DIM, DIM, ls1 + l*DIM, xres);
        ln_kernel<<<ROWS/4, 256, 0, stream>>>(xres, ln2g + l*DIM, ln2b + l*DIM, h);
        gemm_kernel<1><<<dim3(ROWS/64, MLPD/64), 256, 0, stream>>>(h,  W1 + (size_t)l*DIM*MLPD, b1 + l*MLPD, fb, DIM, MLPD, nullptr, nullptr);
        gemm_kernel<2><<<dim3(ROWS/64, DIM/64),  256, 0, stream>>>(fb, W2 + (size_t)l*MLPD*DIM, b2 + l*DIM, nullptr, MLPD, DIM, ls2 + l*DIM, xres);
    }
}